// Round 8
// baseline (264.401 us; speedup 1.0000x reference)
//
#include <hip/hip_runtime.h>
#include <stdint.h>

// ---- types ----
typedef unsigned short u16;
typedef __attribute__((ext_vector_type(4))) float f32x4;
typedef __attribute__((ext_vector_type(8))) __bf16 bf16x8;
typedef __attribute__((ext_vector_type(4))) unsigned int u32x4;

#define HWPX 4096   // H*W pixels
#define NMEM 8192   // T*H*W memory slots
#define CKD  64
#define VROWS 1024  // NOBJ*CV

__device__ __forceinline__ u16 f2bf(float x) {
    union { float f; unsigned u; } v; v.f = x;
    unsigned r = v.u + 0x7FFFu + ((v.u >> 16) & 1u);
    return (u16)(r >> 16);
}

// ============================================================================
// FRAGMENT-ORDER LAYOUTS. One 16B chunk = the 8 bf16 one lane feeds a
// 16x16x32 MFMA: chunk(lane l): row = base+(l&15), k = kk*32+(l>>4)*8+j.
//   Qf [pt 32][h 2][wm 2][mi 4][kk 2][l 64][8]     (1 MB)   rows=p, k=ck
//   Kf [nt 64][h 2][wn 2][ni 4][kk 2][l 64][8]     (2 MB)   rows=n, k=ck
//   Ptf[pB 16][ktg 128][wn 4][ni 4][kk 2][l 64][8] (64 MB)  rows=p, k=n
//   Avf[vt 8][kt 128][wm 2][mi 4][kk 2][l 64][8]   (16 MB)  rows=v, k=n
// ============================================================================

// ---- k1: prep Qf/bsq (16) | Kf (32) | mv->Avf frag-order (32) | out-zero (256)
__global__ void prep_aux(const float* __restrict__ qk, const float* __restrict__ qe,
                         const float* __restrict__ mk, const float* __restrict__ mv,
                         u16* __restrict__ Qf, float* __restrict__ bsq,
                         u16* __restrict__ Kf, u16* __restrict__ Avf,
                         float* __restrict__ outz) {
    const int bx = blockIdx.x;
    const int tid = threadIdx.x;
    if (bx < 16) {
        int p = bx * 256 + tid;   // 4096
        const int pt = p >> 7, wm = (p >> 6) & 1, mi = (p >> 4) & 3, l15 = p & 15;
        const size_t cb = ((((size_t)pt * 2 + 0) * 2 + wm) * 4 + mi) * 2;
        float acc = 0.f;
        #pragma unroll
        for (int cg = 0; cg < 8; ++cg) {
            const int kk = cg >> 2, quad = cg & 3;
            float kv[8], ev[8];
            #pragma unroll
            for (int j = 0; j < 8; ++j) {
                int c = cg * 8 + j;
                kv[j] = qk[c * HWPX + p];
                ev[j] = qe[c * HWPX + p];
                acc += ev[j] * kv[j] * kv[j];
            }
            unsigned w0[4], w1[4];
            #pragma unroll
            for (int jj = 0; jj < 4; ++jj) {
                w0[jj] = (unsigned)f2bf(kv[2*jj] * ev[2*jj]) |
                         ((unsigned)f2bf(kv[2*jj+1] * ev[2*jj+1]) << 16);
                w1[jj] = (unsigned)f2bf(ev[2*jj]) |
                         ((unsigned)f2bf(ev[2*jj+1]) << 16);
            }
            const size_t off = (size_t)quad * 128 + (size_t)l15 * 8;
            *(u32x4*)(Qf + (cb + kk) * 512 + off)      = (u32x4){w0[0], w0[1], w0[2], w0[3]};
            *(u32x4*)(Qf + (cb + 16 + kk) * 512 + off) = (u32x4){w1[0], w1[1], w1[2], w1[3]};
        }
        bsq[p] = acc;
        return;
    }
    if (bx < 48) {
        int n = (bx - 16) * 256 + tid;   // 8192
        const int nt = n >> 7, wn = (n >> 6) & 1, ni = (n >> 4) & 3, l15 = n & 15;
        const size_t cb = ((((size_t)nt * 2 + 0) * 2 + wn) * 4 + ni) * 2;
        #pragma unroll
        for (int cg = 0; cg < 8; ++cg) {
            const int kk = cg >> 2, quad = cg & 3;
            float m[8];
            #pragma unroll
            for (int j = 0; j < 8; ++j)
                m[j] = mk[(cg * 8 + j) * NMEM + n];
            unsigned w0[4], w1[4];
            #pragma unroll
            for (int jj = 0; jj < 4; ++jj) {
                w0[jj] = (unsigned)f2bf(2.f * m[2*jj]) |
                         ((unsigned)f2bf(2.f * m[2*jj+1]) << 16);
                w1[jj] = (unsigned)f2bf(-m[2*jj] * m[2*jj]) |
                         ((unsigned)f2bf(-m[2*jj+1] * m[2*jj+1]) << 16);
            }
            const size_t off = (size_t)quad * 128 + (size_t)l15 * 8;
            *(u32x4*)(Kf + (cb + kk) * 512 + off)      = (u32x4){w0[0], w0[1], w0[2], w0[3]};
            *(u32x4*)(Kf + (cb + 16 + kk) * 512 + off) = (u32x4){w1[0], w1[1], w1[2], w1[3]};
        }
        return;
    }
    if (bx < 80) {               // mv -> Avf frag-order (1024 v x 1024 octets)
        const int idx = (bx - 48) * 256 + tid;   // 0..8191
        const int v = idx >> 3, og = idx & 7;
        const int vt = v >> 7, wm = (v >> 6) & 1, mi = (v >> 4) & 3, l15 = v & 15;
        const float* src = mv + (size_t)v * NMEM + (size_t)og * 1024;
        u16* dbase = Avf + (size_t)vt * 1048576 + wm * 4096 + mi * 1024 + l15 * 8;
        for (int i = 0; i < 128; ++i) {
            const int oct = og * 128 + i;
            float4 f0 = *(const float4*)(src + i * 8);
            float4 f1 = *(const float4*)(src + i * 8 + 4);
            unsigned w0 = (unsigned)f2bf(f0.x) | ((unsigned)f2bf(f0.y) << 16);
            unsigned w1 = (unsigned)f2bf(f0.z) | ((unsigned)f2bf(f0.w) << 16);
            unsigned w2 = (unsigned)f2bf(f1.x) | ((unsigned)f2bf(f1.y) << 16);
            unsigned w3 = (unsigned)f2bf(f1.z) | ((unsigned)f2bf(f1.w) << 16);
            const int kt = oct >> 3, kk = (oct >> 2) & 1, quad = oct & 3;
            *(u32x4*)(dbase + (size_t)kt * 8192 + kk * 512 + quad * 128) =
                (u32x4){w0, w1, w2, w3};
        }
        return;
    }
    {                             // zero out (1M float4s, 4096 per block)
        const int blk = bx - 80;
        #pragma unroll 4
        for (int it = 0; it < 16; ++it) {
            int i = blk * 4096 + it * 256 + tid;
            ((float4*)outz)[i] = make_float4(0.f, 0.f, 0.f, 0.f);
        }
    }
}

// ---- gemm1 tiles: 128p x 128n, direct-reg operands (r4-proven); Pt store
// remapped to the BN=256 Ptf layout (pure index permutation, same bytes).
__launch_bounds__(256, 2)
__global__ void gemm1_tiles(const u16* __restrict__ Qf, const u16* __restrict__ Kf,
                            const float* __restrict__ bsq, const float* __restrict__ ms,
                            u16* __restrict__ Pt, float* __restrict__ dpart) {
    __shared__ __align__(16) u16 smem[17408];   // Ps [128][136] only

    const int tile = blockIdx.x;    // 0..2047
    const int pb = tile & 31;       // p-tile (128 wide)
    const int nb = tile >> 5;       // n-tile (128 wide), 0..63
    const int p0 = pb * 128;
    const int n0 = nb * 128;

    const int tid  = threadIdx.x;
    const int l    = tid & 63;
    const int w    = tid >> 6;
    const int quad = l >> 4;
    const int l15  = l & 15;
    const int wm = w >> 1, wn = w & 1;   // wave tile: 64p x 64n

    f32x4 acc[4][4] = {};

    #pragma unroll
    for (int h = 0; h < 2; ++h) {
        bf16x8 a[4][2], b[4][2];
        const u16* qbase = Qf + ((((size_t)pb * 2 + h) * 2 + wm) * 4096) + (size_t)l * 8;
        const u16* kbase = Kf + ((((size_t)nb * 2 + h) * 2 + wn) * 4096) + (size_t)l * 8;
        #pragma unroll
        for (int mi = 0; mi < 4; ++mi) {
            a[mi][0] = *(const bf16x8*)(qbase + mi * 1024);
            a[mi][1] = *(const bf16x8*)(qbase + mi * 1024 + 512);
        }
        #pragma unroll
        for (int ni = 0; ni < 4; ++ni) {
            b[ni][0] = *(const bf16x8*)(kbase + ni * 1024);
            b[ni][1] = *(const bf16x8*)(kbase + ni * 1024 + 512);
        }
        #pragma unroll
        for (int kk = 0; kk < 2; ++kk)
            #pragma unroll
            for (int mi = 0; mi < 4; ++mi)
                #pragma unroll
                for (int ni = 0; ni < 4; ++ni)
                    acc[mi][ni] = __builtin_amdgcn_mfma_f32_16x16x32_bf16(a[mi][kk], b[ni][kk], acc[mi][ni], 0, 0, 0);
    }

    // per-lane epilogue constants
    float msv[4];
    #pragma unroll
    for (int ni = 0; ni < 4; ++ni)
        msv[ni] = ms[n0 + wn * 64 + ni * 16 + l15] * 0.125f;
    float bsv[4][4];
    #pragma unroll
    for (int mi = 0; mi < 4; ++mi)
        #pragma unroll
        for (int r = 0; r < 4; ++r)
            bsv[mi][r] = bsq[p0 + wm * 64 + mi * 16 + quad * 4 + r];

    u16* Ps = smem;              // [128][136] padded u16
    float rowsum[4][4] = {};
    #pragma unroll
    for (int mi = 0; mi < 4; ++mi) {
        #pragma unroll
        for (int ni = 0; ni < 4; ++ni) {
            f32x4 v = acc[mi][ni];
            int col = wn * 64 + ni * 16 + l15;
            #pragma unroll
            for (int r = 0; r < 4; ++r) {
                int rowl = wm * 64 + mi * 16 + quad * 4 + r;
                float pv = __expf((v[r] - bsv[mi][r]) * msv[ni]);
                rowsum[mi][r] += pv;
                Ps[rowl * 136 + col] = f2bf(pv);
            }
        }
    }
    // butterfly full-reduce over the 16-lane l15 group (16 sums/wave)
    #pragma unroll
    for (int mi = 0; mi < 4; ++mi)
        #pragma unroll
        for (int r = 0; r < 4; ++r) {
            float s = rowsum[mi][r];
            s += __shfl_xor(s, 1);
            s += __shfl_xor(s, 2);
            s += __shfl_xor(s, 4);
            s += __shfl_xor(s, 8);
            rowsum[mi][r] = s;
        }
    // exclusive-slot store: lane l15 owns (mi,r) = (l15>>2, l15&3); all 64 lanes
    {
        float myv = 0.f;
        #pragma unroll
        for (int mi = 0; mi < 4; ++mi)
            #pragma unroll
            for (int r = 0; r < 4; ++r)
                if (l15 == mi * 4 + r) myv = rowsum[mi][r];
        int slice = nb * 2 + wn;   // 0..127 (64-n spans)
        dpart[(size_t)slice * HWPX + p0 + wm * 64 + (l15 >> 2) * 16 + quad * 4 + (l15 & 3)] = myv;
    }
    __syncthreads();

    // Pt store in FRAGMENT ORDER (BN=256 layout): 32 wave-coalesced 1KB chunks
    // p = pB*256 + wn'*64 + ni*16 + l15 with pB = pb>>1, wn' = (pb&1)*2 + wnq
    {
        const size_t dstBase = (size_t)(pb >> 1) * 2097152 + (size_t)(pb & 1) * 2 * 4096;
        #pragma unroll
        for (int it = 0; it < 8; ++it) {
            const int combo = it * 4 + w;              // 0..31
            const int kt  = combo >> 4;                // local k-tile (64 n)
            const int wnq = (combo >> 3) & 1;
            const int niq = (combo >> 1) & 3;
            const int kkq = combo & 1;
            const u32x4* src = (const u32x4*)(Ps + (wnq * 64 + niq * 16 + l15) * 136
                                                 + kt * 64 + kkq * 32 + quad * 8);
            u32x4* dst = (u32x4*)(Pt + dstBase + (size_t)(nb * 2 + kt) * 16384
                                     + wnq * 4096 + niq * 1024 + kkq * 512 + l * 8);
            *dst = *src;
        }
    }
}

// ---- denom: 1/sum over the 128 dpart slices, once per pixel (16 blocks) ----
__global__ void denom_kernel(const float* __restrict__ dpart, float* __restrict__ dinvg) {
    const int p = blockIdx.x * 256 + threadIdx.x;   // 4096
    float s = 0.f;
    #pragma unroll 8
    for (int sl = 0; sl < 128; ++sl)
        s += dpart[(size_t)sl * HWPX + p];
    dinvg[p] = 1.0f / s;
}

// ---------------- GEMM2 v8: pure-register streaming, depth-1 both operands --
// r7 diagnosis: B-loads were depth-0 (issued+used same iter) -> per-iter L3
// latency fully exposed; plus 1.5GB logical cache traffic (BM=64/BN=128).
// v8: BM=128 x BN=256, kz=2 -> logical traffic 768MB; BOTH operands frag-order
// direct-to-reg, cur/nxt double-buffer with full-iteration issue-to-use
// distance; no LDS, no barriers; vmcnt(16) leaves next tile's 16 loads in
// flight. 512 thr / 8 waves (wm2 x wn4, 64x64 wave tiles), grid 256 =
// pBlo(8,XCD) x kz(2) x [pBhi x vb](16). kz=2 -> atomic epilogue (out zeroed).
__launch_bounds__(512, 2)
__global__ void gemm2_kernel(const u16* __restrict__ Avf, const u16* __restrict__ Btf,
                             const float* __restrict__ dinvg, float* __restrict__ outacc) {
    const int tid  = threadIdx.x;
    const int l    = tid & 63;
    const int w    = tid >> 6;      // 0..7
    const int quad = l >> 4;
    const int l15  = l & 15;
    const int wm = w >> 2;          // 0..1 : v-offset wm*64
    const int wn = w & 3;           // 0..3 : p-offset wn*64

    const int pB = blockIdx.x | ((blockIdx.z & 1) << 3);   // 0..15 (XCD = pB&7)
    const int kz = blockIdx.y;                             // 0..1
    const int vb = blockIdx.z >> 1;                        // 0..7
    const int v0 = vb * 128;
    const int p0 = pB * 256;
    const int NT = 64;                                     // K-tiles per kz half

    const u16* abase = Avf + (size_t)vb * 1048576 + (size_t)wm * 4096 + (size_t)l * 8
                           + (size_t)(kz * 64) * 8192;
    const u16* bbase = Btf + (size_t)pB * 2097152 + (size_t)wn * 4096 + (size_t)l * 8
                           + (size_t)(kz * 64) * 16384;

    #define LOADA(dst, t_)                                                       \
        { const u16* ak = abase + (size_t)(t_) * 8192;                           \
          _Pragma("unroll")                                                      \
          for (int mi = 0; mi < 4; ++mi) {                                       \
              dst[mi][0] = *(const bf16x8*)(ak + mi * 1024);                     \
              dst[mi][1] = *(const bf16x8*)(ak + mi * 1024 + 512);               \
          } }
    #define LOADB(dst, t_)                                                       \
        { const u16* bk = bbase + (size_t)(t_) * 16384;                          \
          _Pragma("unroll")                                                      \
          for (int ni = 0; ni < 4; ++ni) {                                       \
              dst[ni][0] = *(const bf16x8*)(bk + ni * 1024);                     \
              dst[ni][1] = *(const bf16x8*)(bk + ni * 1024 + 512);               \
          } }
    #define DOMFMA(A_, B_)                                                       \
        { _Pragma("unroll")                                                      \
          for (int kk = 0; kk < 2; ++kk)                                         \
              _Pragma("unroll")                                                  \
              for (int mi = 0; mi < 4; ++mi)                                     \
                  _Pragma("unroll")                                              \
                  for (int ni = 0; ni < 4; ++ni)                                 \
                      acc[mi][ni] = __builtin_amdgcn_mfma_f32_16x16x32_bf16(     \
                          A_[mi][kk], B_[ni][kk], acc[mi][ni], 0, 0, 0); }

    f32x4 acc[4][4] = {};
    bf16x8 aC[4][2], bC[4][2], aN[4][2], bN[4][2];

    LOADA(aC, 0) LOADB(bC, 0)
    for (int t = 0; t < NT; t += 2) {
        // issue t+1 (always exists: t <= NT-2)
        LOADA(aN, t + 1) LOADB(bN, t + 1)
        __builtin_amdgcn_sched_barrier(0);
        asm volatile("s_waitcnt vmcnt(16)" ::: "memory");   // cur complete; 16 in flight
        __builtin_amdgcn_sched_barrier(0);
        __builtin_amdgcn_s_setprio(1);
        DOMFMA(aC, bC)
        __builtin_amdgcn_s_setprio(0);
        if (t + 2 < NT) {
            LOADA(aC, t + 2) LOADB(bC, t + 2)
            __builtin_amdgcn_sched_barrier(0);
            asm volatile("s_waitcnt vmcnt(16)" ::: "memory");
        } else {
            __builtin_amdgcn_sched_barrier(0);
            asm volatile("s_waitcnt vmcnt(0)" ::: "memory");
        }
        __builtin_amdgcn_sched_barrier(0);
        __builtin_amdgcn_s_setprio(1);
        DOMFMA(aN, bN)
        __builtin_amdgcn_s_setprio(0);
    }
    #undef LOADA
    #undef LOADB
    #undef DOMFMA

    // epilogue: scale by 1/denom, atomic-accumulate (kz=2 partial sums)
    float dinv[4];
    #pragma unroll
    for (int ni = 0; ni < 4; ++ni)
        dinv[ni] = dinvg[p0 + wn * 64 + ni * 16 + l15];

    #pragma unroll
    for (int mi = 0; mi < 4; ++mi) {
        #pragma unroll
        for (int ni = 0; ni < 4; ++ni) {
            int col = p0 + wn * 64 + ni * 16 + l15;
            f32x4 v = acc[mi][ni];
            #pragma unroll
            for (int r = 0; r < 4; ++r) {
                int row = v0 + wm * 64 + mi * 16 + quad * 4 + r;
                atomicAdd(&outacc[(size_t)row * HWPX + col], v[r] * dinv[ni]);
            }
        }
    }
}

// ---------------- launch ----------------
extern "C" void kernel_launch(void* const* d_in, const int* in_sizes, int n_in,
                              void* d_out, int out_size, void* d_ws, size_t ws_size,
                              hipStream_t stream) {
    const float* qk = (const float*)d_in[0];  // (1,64,64,64)
    const float* qe = (const float*)d_in[1];  // (1,64,64,64)
    const float* mk = (const float*)d_in[2];  // (1,64,2,64,64)
    const float* ms = (const float*)d_in[3];  // (1,1,2,64,64)
    const float* mv = (const float*)d_in[4];  // (1,2,512,2,64,64)
    float* out = (float*)d_out;               // (1,2,512,64,64)

    char* ws = (char*)d_ws;
    u16*   Pt    = (u16*)ws;                               // 64 MB  frag-order Ptf (BN=256)
    u16*   Avf   = (u16*)(ws + ((size_t)64 << 20));        // 16 MB  frag-order Avf
    u16*   Kf    = (u16*)(ws + ((size_t)80 << 20));        // 2 MB   frag-order Kf
    u16*   Qf    = (u16*)(ws + ((size_t)82 << 20));        // 1 MB   frag-order Qf
    float* bsq   = (float*)(ws + ((size_t)83 << 20));      // 16 KB
    float* dpart = (float*)(ws + ((size_t)83 << 20) + 65536);           // 2 MB
    float* dinvg = (float*)(ws + ((size_t)83 << 20) + 65536 + (2 << 20)); // 16 KB

    // prep Qf/Kf (48) + mv->Avf (32) + out-zero (256)
    prep_aux<<<336, 256, 0, stream>>>(qk, qe, mk, mv, Qf, bsq, Kf, Avf, out);

    // 2048 gemm1 tiles (128p x 128n)
    gemm1_tiles<<<2048, 256, 0, stream>>>(Qf, Kf, bsq, ms, Pt, dpart);

    // 4096-pixel denom table
    denom_kernel<<<16, 256, 0, stream>>>(dpart, dinvg);

    // 256 blocks = pBlo(8) x kz(2) x [pBhi|vb](16); 512 threads, reg-streaming
    dim3 g2(8, 2, 16);
    gemm2_kernel<<<g2, 512, 0, stream>>>(Avf, Pt, dinvg, out);
}